// Round 6
// baseline (180.893 us; speedup 1.0000x reference)
//
#include <hip/hip_runtime.h>
#include <hip/hip_bf16.h>

#define NB 16384
#define NC 1000
#define NCP 1024          // padded target count (pads score = +inf)
#define ND 1024
#define BM 64
#define BN 256
#define KSTEPS 32         // 1024 / 32
#define NCB 4             // column blocks = NCP / BN

typedef __attribute__((ext_vector_type(8))) short bf16x8;
typedef __attribute__((ext_vector_type(4))) float f32x4;

typedef __attribute__((address_space(1))) const void GV;
typedef __attribute__((address_space(3))) void LV;

__device__ __forceinline__ unsigned short f2bf(float f) {
  union { float f; unsigned u; } c; c.f = f;
  unsigned b = c.u;
  return (unsigned short)((b + 0x7fffu + ((b >> 16) & 1u)) >> 16);  // RNE
}
__device__ __forceinline__ unsigned pk2(float lo, float hi) {
  return ((unsigned)f2bf(hi) << 16) | (unsigned)f2bf(lo);
}

// ---------- prep: target f32 -> bf16 (padded to 1024 rows), exact f32 t2 ----------
__global__ __launch_bounds__(256) void prep_kernel(const float* __restrict__ Tf,
                                                   unsigned short* __restrict__ Tb,
                                                   float* __restrict__ t2) {
  const int c = blockIdx.x;      // 0..1023
  const int tid = threadIdx.x;   // 256 threads, 4 elems each
  if (c >= NC) {
    ushort4 z; z.x = z.y = z.z = z.w = 0;
    ((ushort4*)(Tb + (size_t)c * ND))[tid] = z;
    if (tid == 0) t2[c] = 1e30f;   // padding never wins argmin
    return;
  }
  float4 v = ((const float4*)(Tf + (size_t)c * ND))[tid];
  float ss = v.x * v.x + v.y * v.y + v.z * v.z + v.w * v.w;
  ushort4 o;
  o.x = f2bf(v.x); o.y = f2bf(v.y); o.z = f2bf(v.z); o.w = f2bf(v.w);
  ((ushort4*)(Tb + (size_t)c * ND))[tid] = o;
  #pragma unroll
  for (int m = 1; m < 64; m <<= 1) ss += __shfl_xor(ss, m, 64);
  __shared__ float red[4];
  if ((tid & 63) == 0) red[tid >> 6] = ss;
  __syncthreads();
  if (tid == 0) t2[c] = red[0] + red[1] + red[2] + red[3];
}

// ---------- fused GEMM + mining ----------
// 64x256 tile, BK=32, 4 waves (1x4), wave = 64x64 via 4x4 mfma_16x16x32_bf16.
// Counted-vmcnt pipeline: A is depth-2 reg-prefetched f32->bf16; B via global_load_lds.
__global__ __launch_bounds__(256, 3) void mine3_kernel(
    const float* __restrict__ X, const int* __restrict__ labels,
    const unsigned short* __restrict__ Tb, const float* __restrict__ t2g,
    float* __restrict__ x2g, float* __restrict__ slab, float2* __restrict__ pairs) {
  __shared__ char sA[2][BM * 64];     // [row][64B of k] bf16, 4KB each
  __shared__ char sB[2][BN * 64];     // [col][64B of k] bf16, 16KB each
  __shared__ int sLab[BM];
  __shared__ float2 sMin[BM][4];      // per-row per-wc partial (minval, idx)

  const int tid = threadIdx.x;
  const int lane = tid & 63;
  const int wc = tid >> 6;            // wave = output cols wc*64..+64, rows 0..63
  const int l15 = lane & 15, l4 = lane >> 4;

  // bijective XCD-chunked swizzle: 1024 blocks, 8 XCDs -> contiguous 128-block chunks
  const int bid = (int)blockIdx.x;
  const int wgid = (bid & 7) * 128 + (bid >> 3);
  const int rb = wgid >> 2, cb = wgid & 3;
  const int rowbase = rb * BM, colbase = cb * BN;

  if (tid < BM) sLab[tid] = labels[rowbase + tid];

  // A staging coords: thread t -> row t/4, k-floats (t&3)*8 .. +8
  const float* aptr = X + (size_t)(rowbase + (tid >> 2)) * ND + ((tid & 3) << 3);
  float ss = 0.0f;                    // exact x2 partial (cb==0 blocks only)
  float4 rA0, rA1;                    // depth-2 A prefetch registers

  auto loadA = [&](int kt) {
    rA0 = *(const float4*)(aptr + kt * 32);
    rA1 = *(const float4*)(aptr + kt * 32 + 4);
  };
  auto writeA = [&](int buf) {        // consume rA -> bf16 -> LDS (+x2 accum)
    if (cb == 0) {
      ss += rA0.x * rA0.x + rA0.y * rA0.y + rA0.z * rA0.z + rA0.w * rA0.w
          + rA1.x * rA1.x + rA1.y * rA1.y + rA1.z * rA1.z + rA1.w * rA1.w;
    }
    uint4 w;
    w.x = pk2(rA0.x, rA0.y); w.y = pk2(rA0.z, rA0.w);
    w.z = pk2(rA1.x, rA1.y); w.w = pk2(rA1.z, rA1.w);
    *(uint4*)(sA[buf] + tid * 16) = w;
  };
  auto stageB = [&](int buf, int kt) {
    #pragma unroll
    for (int i = 0; i < 4; ++i) {
      const int o = i * 4096 + tid * 16;   // 16KB B tile, linear dest
      const char* src = (const char*)Tb + (size_t)(colbase + (o >> 6)) * 2048 + kt * 64 + (o & 63);
      __builtin_amdgcn_global_load_lds((GV*)src, (LV*)(sB[buf] + o), 16, 0, 0);
    }
  };

  f32x4 acc[4][4] = {};

  // ---- prologue: stage tile 0, prefetch A tile 1 ----
  loadA(0);
  stageB(0, 0);
  writeA(0);                               // compiler waits the 2 rA loads only
  loadA(1);
  __builtin_amdgcn_sched_barrier(0);
  asm volatile("s_waitcnt vmcnt(2) lgkmcnt(0)\n\ts_barrier" ::: "memory");
  __builtin_amdgcn_sched_barrier(0);

  int cur = 0;
  for (int ks = 0; ks < KSTEPS; ++ks) {
    if (ks + 1 < KSTEPS) {                 // uniform branch
      writeA(cur ^ 1);                     // tile ks+1 (rA), waits its 2 loads
      stageB(cur ^ 1, ks + 1);             // +4 vmem
      const int kn = (ks + 2 < KSTEPS) ? ks + 2 : KSTEPS - 1;
      loadA(kn);                           // +2 vmem (stays in flight across barrier)
    }
    const char* pa = sA[cur];
    const char* pb = sB[cur];
    bf16x8 af[4];
    #pragma unroll
    for (int m = 0; m < 4; ++m)
      af[m] = *(const bf16x8*)(pa + ((m * 16 + l15) * 64 + l4 * 16));
    #pragma unroll
    for (int n = 0; n < 4; ++n) {
      bf16x8 bfr = *(const bf16x8*)(pb + ((wc * 64 + n * 16 + l15) * 64 + l4 * 16));
      #pragma unroll
      for (int m = 0; m < 4; ++m)
        acc[m][n] = __builtin_amdgcn_mfma_f32_16x16x32_bf16(af[m], bfr, acc[m][n], 0, 0, 0);
    }
    // counted drain: B gloads + all LDS ops done; the 2 A-prefetch loads stay in flight
    __builtin_amdgcn_sched_barrier(0);
    asm volatile("s_waitcnt vmcnt(2) lgkmcnt(0)\n\ts_barrier" ::: "memory");
    __builtin_amdgcn_sched_barrier(0);
    cur ^= 1;
  }

  // exact x2 (each X row staged by a fixed thread quad; cb==0 covers all rows once)
  if (cb == 0) {
    ss += __shfl_xor(ss, 1, 64);
    ss += __shfl_xor(ss, 2, 64);
    if ((tid & 3) == 0) x2g[rowbase + (tid >> 2)] = ss;
  }

  // ---- mining epilogue: score = t2[c] - 2*dot; extract lab score; per-row argmin ----
  float t2v[4];
  #pragma unroll
  for (int n = 0; n < 4; ++n) t2v[n] = t2g[colbase + wc * 64 + n * 16 + l15];

  #pragma unroll
  for (int m = 0; m < 4; ++m) {
    #pragma unroll
    for (int j = 0; j < 4; ++j) {
      const int rowl = m * 16 + l4 * 4 + j;
      const int lab = sLab[rowl];
      float bv = 3.0e38f; int bi = 0x7fffffff;
      #pragma unroll
      for (int n = 0; n < 4; ++n) {
        const int col = colbase + wc * 64 + n * 16 + l15;
        const float sc = t2v[n] - 2.0f * acc[m][n][j];
        if (col == lab) slab[rowbase + rowl] = sc;       // d_ap^2 - x2
        const float sce = (col == lab) ? 3.2e38f : sc;
        if (sce < bv || (sce == bv && col < bi)) { bv = sce; bi = col; }
      }
      #pragma unroll
      for (int mk = 1; mk < 16; mk <<= 1) {              // reduce across l15 (cols)
        const float ov = __shfl_xor(bv, mk, 64);
        const int   oi = __shfl_xor(bi, mk, 64);
        if (ov < bv || (ov == bv && oi < bi)) { bv = ov; bi = oi; }
      }
      if (l15 == 0) sMin[rowl][wc] = make_float2(bv, __int_as_float(bi));
    }
  }
  __syncthreads();
  if (tid < BM) {
    float2 p = sMin[tid][0];
    #pragma unroll
    for (int q = 1; q < 4; ++q) {
      float2 o = sMin[tid][q];
      if (o.x < p.x || (o.x == p.x && __float_as_int(o.y) < __float_as_int(p.y))) p = o;
    }
    pairs[(size_t)(rowbase + tid) * NCB + cb] = p;
  }
}

// ---------- finalize: combine col-block partials, hinge, mean ----------
__global__ __launch_bounds__(256) void finalize_kernel(
    const float2* __restrict__ pairs, const float* __restrict__ slab,
    const float* __restrict__ x2g, float* __restrict__ out) {
  const int r = blockIdx.x * 256 + threadIdx.x;
  float2 p = pairs[(size_t)r * NCB];
  #pragma unroll
  for (int q = 1; q < NCB; ++q) {
    float2 o = pairs[(size_t)r * NCB + q];
    if (o.x < p.x || (o.x == p.x && __float_as_int(o.y) < __float_as_int(p.y))) p = o;
  }
  const float x2v = x2g[r];
  const float dap = sqrtf(fmaxf(x2v + slab[r], 0.0f));
  const float dan = sqrtf(fmaxf(x2v + p.x, 0.0f));
  float h = fmaxf(dap - dan + 1.0f, 0.0f);
  #pragma unroll
  for (int mk = 1; mk < 64; mk <<= 1) h += __shfl_xor(h, mk, 64);
  __shared__ float red[4];
  if ((threadIdx.x & 63) == 0) red[threadIdx.x >> 6] = h;
  __syncthreads();
  if (threadIdx.x == 0)
    atomicAdd(out, (red[0] + red[1] + red[2] + red[3]) * (1.0f / (float)NB));
}

extern "C" void kernel_launch(void* const* d_in, const int* in_sizes, int n_in,
                              void* d_out, int out_size, void* d_ws, size_t ws_size,
                              hipStream_t stream) {
  const float* X = (const float*)d_in[0];        // [16384,1024] f32
  const int* labels = (const int*)d_in[1];       // [16384] int
  const float* Tf = (const float*)d_in[2];       // [1000,1024] f32
  float* out = (float*)d_out;                    // scalar f32

  char* ws = (char*)d_ws;
  unsigned short* Tb = (unsigned short*)ws;                       // 2 MB
  float* t2   = (float*)(ws + 2097152);                           // 4 KB
  float* x2   = (float*)(ws + 2097152 + 4096);                    // 64 KB
  float* slab = (float*)(ws + 2097152 + 4096 + 65536);            // 64 KB
  float2* pairs = (float2*)(ws + 2097152 + 4096 + 131072);        // 512 KB

  hipMemsetAsync(d_out, 0, sizeof(float), stream);
  prep_kernel<<<NCP, 256, 0, stream>>>(Tf, Tb, t2);
  mine3_kernel<<<(NB / BM) * NCB, 256, 0, stream>>>(X, labels, Tb, t2, x2, slab, pairs);
  finalize_kernel<<<NB / 256, 256, 0, stream>>>(pairs, slab, x2, out);
}

// Round 7
// 150.194 us; speedup vs baseline: 1.2044x; 1.2044x over previous
//
#include <hip/hip_runtime.h>
#include <hip/hip_bf16.h>

#define NB 16384
#define NC 1000
#define NCP 1024          // padded target count (pads score = +inf)
#define ND 1024
#define BM 128
#define BN 256
#define KSTEPS 32         // 1024 / 32
#define NCB 4             // column blocks = NCP / BN

typedef __attribute__((ext_vector_type(8))) short bf16x8;
typedef __attribute__((ext_vector_type(4))) float f32x4;

typedef __attribute__((address_space(1))) const void GV;
typedef __attribute__((address_space(3))) void LV;

__device__ __forceinline__ unsigned short f2bf(float f) {
  union { float f; unsigned u; } c; c.f = f;
  unsigned b = c.u;
  return (unsigned short)((b + 0x7fffu + ((b >> 16) & 1u)) >> 16);  // RNE
}
__device__ __forceinline__ unsigned pk2(float lo, float hi) {
  return ((unsigned)f2bf(hi) << 16) | (unsigned)f2bf(lo);
}

// ---------- prep: target f32 -> bf16 (padded to 1024 rows), exact f32 t2 ----------
__global__ __launch_bounds__(256) void prep_kernel(const float* __restrict__ Tf,
                                                   unsigned short* __restrict__ Tb,
                                                   float* __restrict__ t2) {
  const int c = blockIdx.x;      // 0..1023
  const int tid = threadIdx.x;   // 256 threads, 4 elems each
  if (c >= NC) {
    ushort4 z; z.x = z.y = z.z = z.w = 0;
    ((ushort4*)(Tb + (size_t)c * ND))[tid] = z;
    if (tid == 0) t2[c] = 1e30f;   // padding never wins argmin
    return;
  }
  float4 v = ((const float4*)(Tf + (size_t)c * ND))[tid];
  float ss = v.x * v.x + v.y * v.y + v.z * v.z + v.w * v.w;
  ushort4 o;
  o.x = f2bf(v.x); o.y = f2bf(v.y); o.z = f2bf(v.z); o.w = f2bf(v.w);
  ((ushort4*)(Tb + (size_t)c * ND))[tid] = o;
  #pragma unroll
  for (int m = 1; m < 64; m <<= 1) ss += __shfl_xor(ss, m, 64);
  __shared__ float red[4];
  if ((tid & 63) == 0) red[tid >> 6] = ss;
  __syncthreads();
  if (tid == 0) t2[c] = red[0] + red[1] + red[2] + red[3];
}

// ---------- prepx: inputs f32 -> bf16 + exact x2 (streaming, ~96MB) ----------
__global__ __launch_bounds__(256) void prepx_kernel(const float* __restrict__ X,
                                                    unsigned short* __restrict__ Xb,
                                                    float* __restrict__ x2) {
  const int r = blockIdx.x;      // 0..16383
  const int tid = threadIdx.x;
  float4 v = ((const float4*)(X + (size_t)r * ND))[tid];
  float ss = v.x * v.x + v.y * v.y + v.z * v.z + v.w * v.w;
  ushort4 o;
  o.x = f2bf(v.x); o.y = f2bf(v.y); o.z = f2bf(v.z); o.w = f2bf(v.w);
  ((ushort4*)(Xb + (size_t)r * ND))[tid] = o;
  #pragma unroll
  for (int m = 1; m < 64; m <<= 1) ss += __shfl_xor(ss, m, 64);
  __shared__ float red[4];
  if ((tid & 63) == 0) red[tid >> 6] = ss;
  __syncthreads();
  if (tid == 0) x2[r] = red[0] + red[1] + red[2] + red[3];
}

// ---------- mine4: pure bf16 GEMM + mining (m97 structure) ----------
// 128x256 tile, BK=32, 8 waves (2x4), wave = 64x64 via 4x4 mfma_16x16x32_bf16.
// Both operands staged via global_load_lds width-16; one __syncthreads per step.
__global__ __launch_bounds__(512, 4) void mine4_kernel(
    const unsigned short* __restrict__ Xb, const int* __restrict__ labels,
    const unsigned short* __restrict__ Tb, const float* __restrict__ t2g,
    float* __restrict__ slab, float2* __restrict__ pairs) {
  __shared__ char sA[2][BM * 64];     // [row][64B of k] bf16, 8KB each
  __shared__ char sB[2][BN * 64];     // [col][64B of k] bf16, 16KB each
  __shared__ int sLab[BM];
  __shared__ float2 sMin[BM][4];      // per-row per-wc partial (minval, idx)

  const int tid = threadIdx.x;
  const int lane = tid & 63;
  const int wid = tid >> 6;
  const int l15 = lane & 15, l4 = lane >> 4;
  const int wr = wid >> 2, wc = wid & 3;

  // bijective XCD-chunked swizzle: 512 blocks, 8 XCDs -> contiguous 64-block chunks
  const int bid = (int)blockIdx.x;
  const int wgid = (bid & 7) * 64 + (bid >> 3);
  const int rb = wgid >> 2, cb = wgid & 3;
  const int rowbase = rb * BM, colbase = cb * BN;

  if (tid < BM) sLab[tid] = labels[rowbase + tid];

  auto stage = [&](int buf, int ks) {
    {  // A tile: 8KB, thread t -> 16B at row o>>6, k-bytes ks*64 + (o&63)
      const int o = tid * 16;
      const char* src = (const char*)Xb + (size_t)(rowbase + (o >> 6)) * 2048 + ks * 64 + (o & 63);
      __builtin_amdgcn_global_load_lds((GV*)src, (LV*)(sA[buf] + o), 16, 0, 0);
    }
    #pragma unroll
    for (int i = 0; i < 2; ++i) {  // B tile: 16KB
      const int o = i * 8192 + tid * 16;
      const char* src = (const char*)Tb + (size_t)(colbase + (o >> 6)) * 2048 + ks * 64 + (o & 63);
      __builtin_amdgcn_global_load_lds((GV*)src, (LV*)(sB[buf] + o), 16, 0, 0);
    }
  };

  f32x4 acc[4][4] = {};
  stage(0, 0);
  int cur = 0;
  for (int ks = 0; ks < KSTEPS; ++ks) {
    __syncthreads();                                   // buf[cur] staged (vmcnt drained)
    if (ks + 1 < KSTEPS) stage(cur ^ 1, ks + 1);
    const char* pa = sA[cur];
    const char* pb = sB[cur];
    bf16x8 af[4];
    #pragma unroll
    for (int m = 0; m < 4; ++m)
      af[m] = *(const bf16x8*)(pa + ((wr * 64 + m * 16 + l15) * 64 + l4 * 16));
    #pragma unroll
    for (int n = 0; n < 4; ++n) {
      bf16x8 bfr = *(const bf16x8*)(pb + ((wc * 64 + n * 16 + l15) * 64 + l4 * 16));
      #pragma unroll
      for (int m = 0; m < 4; ++m)
        acc[m][n] = __builtin_amdgcn_mfma_f32_16x16x32_bf16(af[m], bfr, acc[m][n], 0, 0, 0);
    }
    cur ^= 1;
  }

  // ---- mining epilogue: score = t2[c] - 2*dot; extract lab score; per-row argmin ----
  float t2v[4];
  #pragma unroll
  for (int n = 0; n < 4; ++n) t2v[n] = t2g[colbase + wc * 64 + n * 16 + l15];

  #pragma unroll
  for (int m = 0; m < 4; ++m) {
    #pragma unroll
    for (int j = 0; j < 4; ++j) {
      const int rowl = wr * 64 + m * 16 + l4 * 4 + j;
      const int lab = sLab[rowl];
      float bv = 3.0e38f; int bi = 0x7fffffff;
      #pragma unroll
      for (int n = 0; n < 4; ++n) {
        const int col = colbase + wc * 64 + n * 16 + l15;
        const float sc = t2v[n] - 2.0f * acc[m][n][j];
        if (col == lab) slab[rowbase + rowl] = sc;       // d_ap^2 - x2
        const float sce = (col == lab) ? 3.2e38f : sc;
        if (sce < bv || (sce == bv && col < bi)) { bv = sce; bi = col; }
      }
      #pragma unroll
      for (int mk = 1; mk < 16; mk <<= 1) {              // reduce across l15 (cols)
        const float ov = __shfl_xor(bv, mk, 64);
        const int   oi = __shfl_xor(bi, mk, 64);
        if (ov < bv || (ov == bv && oi < bi)) { bv = ov; bi = oi; }
      }
      if (l15 == 0) sMin[rowl][wc] = make_float2(bv, __int_as_float(bi));
    }
  }
  __syncthreads();
  if (tid < BM) {
    float2 p = sMin[tid][0];
    #pragma unroll
    for (int q = 1; q < 4; ++q) {
      float2 o = sMin[tid][q];
      if (o.x < p.x || (o.x == p.x && __float_as_int(o.y) < __float_as_int(p.y))) p = o;
    }
    pairs[(size_t)(rowbase + tid) * NCB + cb] = p;
  }
}

// ---------- fallback (ws too small): R2's proven fused kernel, 74.5us ----------
__global__ __launch_bounds__(512, 4) void mine2_kernel(
    const float* __restrict__ X, const int* __restrict__ labels,
    const unsigned short* __restrict__ Tb, const float* __restrict__ t2g,
    float* __restrict__ x2g, float* __restrict__ slab, float2* __restrict__ pairs) {
  __shared__ char sA[2][BM * 64];
  __shared__ char sB[2][BN * 64];
  __shared__ int sLab[BM];
  __shared__ float2 sMin[BM][4];

  const int tid = threadIdx.x;
  const int lane = tid & 63;
  const int wid = tid >> 6;
  const int l15 = lane & 15, l4 = lane >> 4;
  const int wr = wid >> 2, wc = wid & 3;
  const int rb = (int)blockIdx.x >> 2, cb = (int)blockIdx.x & 3;
  const int rowbase = rb * BM, colbase = cb * BN;

  if (tid < BM) sLab[tid] = labels[rowbase + tid];

  const int arow = tid >> 2;
  const float* aptr = X + (size_t)(rowbase + arow) * ND + ((tid & 3) << 3);
  float ss = 0.0f;

  f32x4 acc[4][4] = {};
  int cur = 0;

  auto stage = [&](int buf, int ks) {
    #pragma unroll
    for (int i = 0; i < 2; ++i) {
      const int o = i * 8192 + tid * 16;
      const char* src = (const char*)Tb + (size_t)(colbase + (o >> 6)) * 2048 + ks * 64 + (o & 63);
      __builtin_amdgcn_global_load_lds((GV*)src, (LV*)(sB[buf] + o), 16, 0, 0);
    }
    float4 v0 = *(const float4*)(aptr + ks * 32);
    float4 v1 = *(const float4*)(aptr + ks * 32 + 4);
    if (cb == 0) {
      ss += v0.x * v0.x + v0.y * v0.y + v0.z * v0.z + v0.w * v0.w
          + v1.x * v1.x + v1.y * v1.y + v1.z * v1.z + v1.w * v1.w;
    }
    uint4 w;
    w.x = pk2(v0.x, v0.y); w.y = pk2(v0.z, v0.w);
    w.z = pk2(v1.x, v1.y); w.w = pk2(v1.z, v1.w);
    *(uint4*)(sA[buf] + tid * 16) = w;
  };

  stage(0, 0);
  for (int ks = 0; ks < KSTEPS; ++ks) {
    __syncthreads();
    if (ks + 1 < KSTEPS) stage(cur ^ 1, ks + 1);
    const char* pa = sA[cur];
    const char* pb = sB[cur];
    bf16x8 af[4];
    #pragma unroll
    for (int m = 0; m < 4; ++m)
      af[m] = *(const bf16x8*)(pa + ((wr * 64 + m * 16 + l15) * 64 + l4 * 16));
    #pragma unroll
    for (int n = 0; n < 4; ++n) {
      bf16x8 bfr = *(const bf16x8*)(pb + ((wc * 64 + n * 16 + l15) * 64 + l4 * 16));
      #pragma unroll
      for (int m = 0; m < 4; ++m)
        acc[m][n] = __builtin_amdgcn_mfma_f32_16x16x32_bf16(af[m], bfr, acc[m][n], 0, 0, 0);
    }
    cur ^= 1;
  }

  if (cb == 0) {
    ss += __shfl_xor(ss, 1, 64);
    ss += __shfl_xor(ss, 2, 64);
    if ((tid & 3) == 0) x2g[rowbase + arow] = ss;
  }

  float t2v[4];
  #pragma unroll
  for (int n = 0; n < 4; ++n) t2v[n] = t2g[colbase + wc * 64 + n * 16 + l15];

  #pragma unroll
  for (int m = 0; m < 4; ++m) {
    #pragma unroll
    for (int j = 0; j < 4; ++j) {
      const int rowl = wr * 64 + m * 16 + l4 * 4 + j;
      const int lab = sLab[rowl];
      float bv = 3.0e38f; int bi = 0x7fffffff;
      #pragma unroll
      for (int n = 0; n < 4; ++n) {
        const int col = colbase + wc * 64 + n * 16 + l15;
        const float sc = t2v[n] - 2.0f * acc[m][n][j];
        if (col == lab) slab[rowbase + rowl] = sc;
        const float sce = (col == lab) ? 3.2e38f : sc;
        if (sce < bv || (sce == bv && col < bi)) { bv = sce; bi = col; }
      }
      #pragma unroll
      for (int mk = 1; mk < 16; mk <<= 1) {
        const float ov = __shfl_xor(bv, mk, 64);
        const int   oi = __shfl_xor(bi, mk, 64);
        if (ov < bv || (ov == bv && oi < bi)) { bv = ov; bi = oi; }
      }
      if (l15 == 0) sMin[rowl][wc] = make_float2(bv, __int_as_float(bi));
    }
  }
  __syncthreads();
  if (tid < BM) {
    float2 p = sMin[tid][0];
    #pragma unroll
    for (int q = 1; q < 4; ++q) {
      float2 o = sMin[tid][q];
      if (o.x < p.x || (o.x == p.x && __float_as_int(o.y) < __float_as_int(p.y))) p = o;
    }
    pairs[(size_t)(rowbase + tid) * NCB + cb] = p;
  }
}

// ---------- finalize: combine col-block partials, hinge, mean ----------
__global__ __launch_bounds__(256) void finalize_kernel(
    const float2* __restrict__ pairs, const float* __restrict__ slab,
    const float* __restrict__ x2g, float* __restrict__ out) {
  const int r = blockIdx.x * 256 + threadIdx.x;
  float2 p = pairs[(size_t)r * NCB];
  #pragma unroll
  for (int q = 1; q < NCB; ++q) {
    float2 o = pairs[(size_t)r * NCB + q];
    if (o.x < p.x || (o.x == p.x && __float_as_int(o.y) < __float_as_int(p.y))) p = o;
  }
  const float x2v = x2g[r];
  const float dap = sqrtf(fmaxf(x2v + slab[r], 0.0f));
  const float dan = sqrtf(fmaxf(x2v + p.x, 0.0f));
  float h = fmaxf(dap - dan + 1.0f, 0.0f);
  #pragma unroll
  for (int mk = 1; mk < 64; mk <<= 1) h += __shfl_xor(h, mk, 64);
  __shared__ float red[4];
  if ((threadIdx.x & 63) == 0) red[threadIdx.x >> 6] = h;
  __syncthreads();
  if (threadIdx.x == 0)
    atomicAdd(out, (red[0] + red[1] + red[2] + red[3]) * (1.0f / (float)NB));
}

extern "C" void kernel_launch(void* const* d_in, const int* in_sizes, int n_in,
                              void* d_out, int out_size, void* d_ws, size_t ws_size,
                              hipStream_t stream) {
  const float* X = (const float*)d_in[0];        // [16384,1024] f32
  const int* labels = (const int*)d_in[1];       // [16384] int
  const float* Tf = (const float*)d_in[2];       // [1000,1024] f32
  float* out = (float*)d_out;                    // scalar f32

  char* ws = (char*)d_ws;
  unsigned short* Tb = (unsigned short*)ws;                       // 2 MB
  float* t2   = (float*)(ws + 2097152);                           // 4 KB
  float* x2   = (float*)(ws + 2097152 + 4096);                    // 64 KB
  float* slab = (float*)(ws + 2097152 + 4096 + 65536);            // 64 KB
  float2* pairs = (float2*)(ws + 2097152 + 4096 + 131072);        // 512 KB
  unsigned short* Xb = (unsigned short*)(ws + 2756608);           // 33.5 MB

  const size_t NEED = 2756608u + (size_t)NB * ND * 2u;            // 36,311,040 B

  hipMemsetAsync(d_out, 0, sizeof(float), stream);
  prep_kernel<<<NCP, 256, 0, stream>>>(Tf, Tb, t2);
  if (ws_size >= NEED) {
    prepx_kernel<<<NB, 256, 0, stream>>>(X, Xb, x2);
    mine4_kernel<<<(NB / BM) * NCB, 512, 0, stream>>>(Xb, labels, Tb, t2, slab, pairs);
  } else {
    mine2_kernel<<<(NB / BM) * NCB, 512, 0, stream>>>(X, labels, Tb, t2, x2, slab, pairs);
  }
  finalize_kernel<<<NB / 256, 256, 0, stream>>>(pairs, slab, x2, out);
}